// Round 2
// baseline (51332.593 us; speedup 1.0000x reference)
//
#include <hip/hip_runtime.h>

// LSTM: L=2, B=64, T=512, H=1024
#define BB 64
#define TT 512
#define HH 1024
#define NL 2
#define G4 4096   // 4H
#define D2 2048   // 2H
#define TC 64     // timestep chunk for Gx buffer
#define NCHUNK (TT / TC)

typedef __attribute__((ext_vector_type(8))) short bf16x8;
typedef __attribute__((ext_vector_type(4))) float f32x4;

__device__ inline unsigned short f2bf(float f) {
  union { float f; unsigned u; } v; v.f = f;
  unsigned r = v.u + 0x7FFFu + ((v.u >> 16) & 1u);
  return (unsigned short)(r >> 16);
}

__device__ inline float sigm(float x) { return 1.0f / (1.0f + __expf(-x)); }
// tanh(x) = 2/(1+e^{-2x}) - 1 ; saturates correctly at +/-inf
__device__ inline float tanhfast(float x) { return 2.0f / (1.0f + __expf(-2.0f * x)) - 1.0f; }

// ---------------- fp32 -> bf16 bulk convert ----------------
__global__ __launch_bounds__(256) void k_cvt(const float* __restrict__ src,
                                             unsigned short* __restrict__ dst, int n4) {
  int i = blockIdx.x * blockDim.x + threadIdx.x;
  int stride = gridDim.x * blockDim.x;
  for (; i < n4; i += stride) {
    float4 v = ((const float4*)src)[i];
    ushort4 o;
    o.x = f2bf(v.x); o.y = f2bf(v.y); o.z = f2bf(v.z); o.w = f2bf(v.w);
    ((ushort4*)dst)[i] = o;
  }
}

__global__ void k_zero(unsigned* __restrict__ p, int n) {
  int i = blockIdx.x * blockDim.x + threadIdx.x;
  if (i < n) p[i] = 0;
}

// bperm[l][nn] = bias[l][ (nn&3)*H + (nn>>2) ]   (interleaved gate order)
__global__ void k_biasperm(const float* __restrict__ b_in, float* __restrict__ bperm) {
  int i = blockIdx.x * blockDim.x + threadIdx.x;
  if (i < NL * G4) {
    int l = i >> 12, nn = i & 4095;
    bperm[i] = b_in[l * G4 + (nn & 3) * HH + (nn >> 2)];
  }
}

__global__ void k_init(const float* __restrict__ h0, const float* __restrict__ c0,
                       unsigned short* __restrict__ hbf0, float* __restrict__ cst, int l) {
  int i = blockIdx.x * blockDim.x + threadIdx.x;
  if (i < BB * HH) {
    hbf0[i] = f2bf(h0[l * BB * HH + i]);
    cst[i] = c0[l * BB * HH + i];
  }
}

// ---------------- x-projection GEMM (unchanged, verified) ----------------
__global__ __launch_bounds__(256) void k_xgemm(const unsigned short* __restrict__ xbf,
                                               const unsigned short* __restrict__ wbf,
                                               const float* __restrict__ bperm,
                                               float* __restrict__ gx,
                                               int layer, int t0) {
  __shared__ short lds[2 * 8192];
  short* Ald = lds;
  short* Bld = lds + 8192;
  const int tid = threadIdx.x;
  const int lane = tid & 63;
  const int w = tid >> 6;
  const int bx = blockIdx.x, by = blockIdx.y;
  const unsigned short* wb = wbf + (size_t)layer * G4 * D2;

  f32x4 acc[4][4] = {};
  const int pslot = lane & 7;

  for (int kc = 0; kc < 16; ++kc) {
    __syncthreads();
    const int k0 = kc * 64;
#pragma unroll
    for (int i = 0; i < 4; ++i) {
      int r = (w * 4 + i) * 8 + (lane >> 3);
      int lslot = pslot ^ (r & 7);
      {
        int mg = by * 128 + r;
        int b = mg & 63, t = t0 + (mg >> 6);
        const unsigned short* src = xbf + ((size_t)(b * TT + t)) * HH + k0 + lslot * 8;
        __builtin_amdgcn_global_load_lds((const __attribute__((address_space(1))) void*)src,
                                         (__attribute__((address_space(3))) void*)(Ald + (w * 4 + i) * 512),
                                         16, 0, 0);
      }
      {
        int ng = bx * 128 + r;
        int wrow = (ng & 3) * HH + (ng >> 2);
        const unsigned short* src = wb + (size_t)wrow * D2 + k0 + lslot * 8;
        __builtin_amdgcn_global_load_lds((const __attribute__((address_space(1))) void*)src,
                                         (__attribute__((address_space(3))) void*)(Bld + (w * 4 + i) * 512),
                                         16, 0, 0);
      }
    }
    asm volatile("s_waitcnt vmcnt(0)" ::: "memory");
    __syncthreads();

#pragma unroll
    for (int kk = 0; kk < 2; ++kk) {
      bf16x8 afr[4], bfr[4];
      int ls = kk * 4 + (lane >> 4);
#pragma unroll
      for (int f = 0; f < 4; ++f) {
        int ra = (w >> 1) * 64 + f * 16 + (lane & 15);
        int ps = ls ^ (ra & 7);
        afr[f] = *(const bf16x8*)((const char*)Ald + ra * 128 + ps * 16);
        int rb = (w & 1) * 64 + f * 16 + (lane & 15);
        int psb = ls ^ (rb & 7);
        bfr[f] = *(const bf16x8*)((const char*)Bld + rb * 128 + psb * 16);
      }
#pragma unroll
      for (int fi = 0; fi < 4; ++fi)
#pragma unroll
        for (int fj = 0; fj < 4; ++fj)
          acc[fi][fj] = __builtin_amdgcn_mfma_f32_16x16x32_bf16(afr[fi], bfr[fj], acc[fi][fj], 0, 0, 0);
    }
  }

  const float* bp = bperm + layer * G4;
#pragma unroll
  for (int fj = 0; fj < 4; ++fj) {
    int col = bx * 128 + (w & 1) * 64 + fj * 16 + (lane & 15);
    float bv = bp[col];
#pragma unroll
    for (int fi = 0; fi < 4; ++fi) {
      int mg = by * 128 + (w >> 1) * 64 + fi * 16 + (lane >> 4) * 4;
#pragma unroll
      for (int r = 0; r < 4; ++r)
        gx[(size_t)(mg + r) * G4 + col] = acc[fi][fj][r] + bv;
    }
  }
}

// ---------------- persistent recurrent chunk: 64 steps, flag-sync ----------------
// 256 WGs x 256 thr (all co-resident: 37KB LDS, tiny VGPR). WG wg owns 16
// interleaved gate-cols = hidden units [wg*4, wg*4+4) x 4 gates. Wh slice
// staged once into XOR-swizzled LDS. Per step: poll prev-step flags (wave 0,
// acquire, 64 uints = 256 byte-flags), MFMA K=1024, LDS gate exchange,
// elementwise update, global h write, fence, release flag.
__global__ __launch_bounds__(256) void k_steps64(unsigned short* __restrict__ hbf,
                                                 const unsigned short* __restrict__ wbf,
                                                 const float* __restrict__ gx,
                                                 float* __restrict__ cst,
                                                 float* __restrict__ dout,
                                                 unsigned short* __restrict__ xnext,
                                                 unsigned char* __restrict__ flags,
                                                 int layer, int t0) {
  __shared__ short Wld[16 * 1024];
  __shared__ float gl[64 * 20];
  const int tid = threadIdx.x;
  const int lane = tid & 63;
  const int w = tid >> 6;
  const int wg = blockIdx.x;

  // Stage Wh slice (16 gate-cols x K=1024), XOR-swizzled on 16B granules.
  {
    const unsigned short* wb = wbf + (size_t)layer * G4 * D2 + HH;  // recurrent half
    for (int i = tid; i < 2048; i += 256) {
      int col = i >> 7;    // 0..15
      int g = i & 127;     // 16B granule within row
      int ng = wg * 16 + col;
      bf16x8 v = *(const bf16x8*)(wb + (size_t)((ng & 3) * HH + (ng >> 2)) * D2 + g * 8);
      ((bf16x8*)Wld)[col * 128 + (g ^ (col & 7))] = v;
    }
  }
  __syncthreads();

  const int bq = w * 16 + (lane & 15);  // batch row this lane loads for A
  const int kq = (lane >> 4) * 8;
  const int wcol = lane & 15;
  const int wslot0 = (lane >> 4);
  const int wx = lane & 7;

  for (int tt = 0; tt < TC; ++tt) {
    const int t = t0 + tt;

    if (tt > 0) {
      if (tid < 64) {
        const unsigned* fr = (const unsigned*)(flags + ((size_t)(t - 1)) * 256);
        while (1) {
          unsigned v = __hip_atomic_load(fr + tid, __ATOMIC_ACQUIRE, __HIP_MEMORY_SCOPE_AGENT);
          if (__all(v == 0x01010101u)) break;
          __builtin_amdgcn_s_sleep(1);
        }
      }
      __syncthreads();
    }

    const unsigned short* asrc = hbf + (size_t)(t & 1) * (BB * HH) + (size_t)bq * HH + kq;

    f32x4 acc0 = {0.f, 0.f, 0.f, 0.f}, acc1 = {0.f, 0.f, 0.f, 0.f};
#pragma unroll
    for (int ks = 0; ks < 32; ks += 2) {
      bf16x8 a0 = *(const bf16x8*)(asrc + ks * 32);
      bf16x8 b0 = ((const bf16x8*)Wld)[wcol * 128 + ((ks * 4 + wslot0) ^ wx)];
      acc0 = __builtin_amdgcn_mfma_f32_16x16x32_bf16(a0, b0, acc0, 0, 0, 0);
      bf16x8 a1 = *(const bf16x8*)(asrc + ks * 32 + 32);
      bf16x8 b1 = ((const bf16x8*)Wld)[wcol * 128 + (((ks + 1) * 4 + wslot0) ^ wx)];
      acc1 = __builtin_amdgcn_mfma_f32_16x16x32_bf16(a1, b1, acc1, 0, 0, 0);
    }
    f32x4 acc = acc0 + acc1;

    {
      int row = w * 16 + (lane >> 4) * 4;
      int col = lane & 15;
#pragma unroll
      for (int r = 0; r < 4; ++r) gl[(row + r) * 20 + col] = acc[r];
    }
    __syncthreads();

    {
      int b = tid >> 2, j = tid & 3;
      int u = wg * 4 + j;
      float f = gl[b * 20 + j * 4 + 0];
      float i = gl[b * 20 + j * 4 + 1];
      float g = gl[b * 20 + j * 4 + 2];
      float o = gl[b * 20 + j * 4 + 3];
      const float4 gx4 = *(const float4*)(gx + ((size_t)(tt * BB + b)) * G4 + u * 4);
      f += gx4.x; i += gx4.y; g += gx4.z; o += gx4.w;
      float c_old = cst[b * HH + u];
      float cn = sigm(f) * c_old + sigm(i) * tanhfast(g);
      float hn = sigm(o) * tanhfast(cn);
      cst[b * HH + u] = cn;
      unsigned short hb = f2bf(hn);
      hbf[(size_t)((t + 1) & 1) * (BB * HH) + b * HH + u] = hb;
      if (xnext) {
        xnext[((size_t)b * TT + t) * HH + u] = hb;
        if (t == TT - 1) dout[((size_t)b * TT + t) * HH + u] = hn;  // only last step needed
      } else {
        dout[((size_t)b * TT + t) * HH + u] = hn;
      }
    }
    __threadfence();
    __syncthreads();
    if (tid == 0)
      __hip_atomic_store(flags + (size_t)t * 256 + wg, (unsigned char)1,
                         __ATOMIC_RELEASE, __HIP_MEMORY_SCOPE_AGENT);
  }
}

// h_n[l] = out[:, T-1, :], c_n[l] = c_state
__global__ void k_finals(const float* __restrict__ cst, float* __restrict__ dout, int layer) {
  int i = blockIdx.x * blockDim.x + threadIdx.x;
  if (i < BB * HH) {
    int b = i >> 10, u = i & 1023;
    dout[(size_t)BB * TT * HH + (size_t)layer * BB * HH + i] =
        dout[((size_t)b * TT + (TT - 1)) * HH + u];
    dout[(size_t)BB * TT * HH + (size_t)NL * BB * HH + (size_t)layer * BB * HH + i] = cst[i];
  }
}

extern "C" void kernel_launch(void* const* d_in, const int* in_sizes, int n_in,
                              void* d_out, int out_size, void* d_ws, size_t ws_size,
                              hipStream_t stream) {
  const float* x = (const float*)d_in[0];
  const float* W = (const float*)d_in[1];
  const float* bias = (const float*)d_in[2];
  const float* h0 = (const float*)d_in[3];
  const float* c0 = (const float*)d_in[4];
  float* out = (float*)d_out;

  char* ws = (char*)d_ws;
  unsigned short* wbf = (unsigned short*)(ws + 0);            // 33,554,432 B
  unsigned short* xbf = (unsigned short*)(ws + 33554432);     // 67,108,864 B
  float* gx = (float*)(ws + 100663296);                       // 67,108,864 B
  unsigned short* hbf = (unsigned short*)(ws + 167772160);    // 262,144 B
  float* cst = (float*)(ws + 168034304);                      // 262,144 B
  float* bperm = (float*)(ws + 168296448);                    // 32,768 B
  unsigned char* flags = (unsigned char*)(ws + 168329216);    // 262,144 B (2*512*256)
  // total ws use: ~168.6 MB

  k_zero<<<256, 256, 0, stream>>>((unsigned*)flags, NL * TT * 256 / 4);
  k_cvt<<<2048, 256, 0, stream>>>(W, wbf, NL * G4 * D2 / 4);
  k_cvt<<<2048, 256, 0, stream>>>(x, xbf, BB * TT * HH / 4);
  k_biasperm<<<(NL * G4 + 255) / 256, 256, 0, stream>>>(bias, bperm);

  for (int l = 0; l < NL; ++l) {
    k_init<<<BB * HH / 256, 256, 0, stream>>>(h0, c0, hbf, cst, l);
    for (int c = 0; c < NCHUNK; ++c) {
      k_xgemm<<<dim3(32, 32), 256, 0, stream>>>(xbf, wbf, bperm, gx, l, c * TC);
      k_steps64<<<256, 256, 0, stream>>>(hbf, wbf, gx, cst, out,
                                         (l == 0) ? xbf : (unsigned short*)nullptr,
                                         flags + (size_t)l * TT * 256, l, c * TC);
    }
    k_finals<<<256, 256, 0, stream>>>(cst, out, l);
  }
}

// Round 3
// 6438.145 us; speedup vs baseline: 7.9732x; 7.9732x over previous
//
#include <hip/hip_runtime.h>

// LSTM: L=2, B=64, T=512, H=1024
#define BB 64
#define TT 512
#define HH 1024
#define NL 2
#define G4 4096   // 4H
#define D2 2048   // 2H
#define TC 64     // timestep chunk for Gx buffer
#define NCHUNK (TT / TC)

typedef __attribute__((ext_vector_type(8))) short bf16x8;
typedef __attribute__((ext_vector_type(4))) float f32x4;

__device__ inline unsigned short f2bf(float f) {
  union { float f; unsigned u; } v; v.f = f;
  unsigned r = v.u + 0x7FFFu + ((v.u >> 16) & 1u);
  return (unsigned short)(r >> 16);
}

__device__ inline float sigm(float x) { return 1.0f / (1.0f + __expf(-x)); }
__device__ inline float tanhfast(float x) { return 2.0f / (1.0f + __expf(-2.0f * x)) - 1.0f; }

// ---- LLC-coherent (cross-XCD) access helpers: sc0 sc1 = bypass L1+L2 ----
__device__ inline bf16x8 ld_h16(const unsigned short* p) {
  bf16x8 r;
  asm volatile("global_load_dwordx4 %0, %1, off sc0 sc1"
               : "=v"(r) : "v"(p) : "memory");
  return r;
}
__device__ inline unsigned ld_flag(const unsigned* p) {
  unsigned r;
  asm volatile("global_load_dword %0, %1, off sc0 sc1\n\t"
               "s_waitcnt vmcnt(0)"
               : "=v"(r) : "v"(p) : "memory");
  return r;
}
__device__ inline void st_flag(unsigned* p, unsigned v) {
  asm volatile("global_store_dword %0, %1, off sc0 sc1"
               :: "v"(p), "v"(v) : "memory");
}
__device__ inline void st_h32(unsigned short* p, unsigned v) {
  asm volatile("global_store_dword %0, %1, off sc0 sc1"
               :: "v"(p), "v"(v) : "memory");
}

// ---------------- fp32 -> bf16 bulk convert ----------------
__global__ __launch_bounds__(256) void k_cvt(const float* __restrict__ src,
                                             unsigned short* __restrict__ dst, int n4) {
  int i = blockIdx.x * blockDim.x + threadIdx.x;
  int stride = gridDim.x * blockDim.x;
  for (; i < n4; i += stride) {
    float4 v = ((const float4*)src)[i];
    ushort4 o;
    o.x = f2bf(v.x); o.y = f2bf(v.y); o.z = f2bf(v.z); o.w = f2bf(v.w);
    ((ushort4*)dst)[i] = o;
  }
}

__global__ void k_zero(unsigned* __restrict__ p, int n) {
  int i = blockIdx.x * blockDim.x + threadIdx.x;
  if (i < n) p[i] = 0;
}

__global__ void k_biasperm(const float* __restrict__ b_in, float* __restrict__ bperm) {
  int i = blockIdx.x * blockDim.x + threadIdx.x;
  if (i < NL * G4) {
    int l = i >> 12, nn = i & 4095;
    bperm[i] = b_in[l * G4 + (nn & 3) * HH + (nn >> 2)];
  }
}

__global__ void k_init(const float* __restrict__ h0, const float* __restrict__ c0,
                       unsigned short* __restrict__ hbf0, float* __restrict__ cst, int l) {
  int i = blockIdx.x * blockDim.x + threadIdx.x;
  if (i < BB * HH) {
    hbf0[i] = f2bf(h0[l * BB * HH + i]);
    cst[i] = c0[l * BB * HH + i];
  }
}

// ---------------- x-projection GEMM (verified in R1/R2) ----------------
__global__ __launch_bounds__(256) void k_xgemm(const unsigned short* __restrict__ xbf,
                                               const unsigned short* __restrict__ wbf,
                                               const float* __restrict__ bperm,
                                               float* __restrict__ gx,
                                               int layer, int t0) {
  __shared__ short lds[2 * 8192];
  short* Ald = lds;
  short* Bld = lds + 8192;
  const int tid = threadIdx.x;
  const int lane = tid & 63;
  const int w = tid >> 6;
  const int bx = blockIdx.x, by = blockIdx.y;
  const unsigned short* wb = wbf + (size_t)layer * G4 * D2;

  f32x4 acc[4][4] = {};
  const int pslot = lane & 7;

  for (int kc = 0; kc < 16; ++kc) {
    __syncthreads();
    const int k0 = kc * 64;
#pragma unroll
    for (int i = 0; i < 4; ++i) {
      int r = (w * 4 + i) * 8 + (lane >> 3);
      int lslot = pslot ^ (r & 7);
      {
        int mg = by * 128 + r;
        int b = mg & 63, t = t0 + (mg >> 6);
        const unsigned short* src = xbf + ((size_t)(b * TT + t)) * HH + k0 + lslot * 8;
        __builtin_amdgcn_global_load_lds((const __attribute__((address_space(1))) void*)src,
                                         (__attribute__((address_space(3))) void*)(Ald + (w * 4 + i) * 512),
                                         16, 0, 0);
      }
      {
        int ng = bx * 128 + r;
        int wrow = (ng & 3) * HH + (ng >> 2);
        const unsigned short* src = wb + (size_t)wrow * D2 + k0 + lslot * 8;
        __builtin_amdgcn_global_load_lds((const __attribute__((address_space(1))) void*)src,
                                         (__attribute__((address_space(3))) void*)(Bld + (w * 4 + i) * 512),
                                         16, 0, 0);
      }
    }
    asm volatile("s_waitcnt vmcnt(0)" ::: "memory");
    __syncthreads();

#pragma unroll
    for (int kk = 0; kk < 2; ++kk) {
      bf16x8 afr[4], bfr[4];
      int ls = kk * 4 + (lane >> 4);
#pragma unroll
      for (int f = 0; f < 4; ++f) {
        int ra = (w >> 1) * 64 + f * 16 + (lane & 15);
        int ps = ls ^ (ra & 7);
        afr[f] = *(const bf16x8*)((const char*)Ald + ra * 128 + ps * 16);
        int rb = (w & 1) * 64 + f * 16 + (lane & 15);
        int psb = ls ^ (rb & 7);
        bfr[f] = *(const bf16x8*)((const char*)Bld + rb * 128 + psb * 16);
      }
#pragma unroll
      for (int fi = 0; fi < 4; ++fi)
#pragma unroll
        for (int fj = 0; fj < 4; ++fj)
          acc[fi][fj] = __builtin_amdgcn_mfma_f32_16x16x32_bf16(afr[fi], bfr[fj], acc[fi][fj], 0, 0, 0);
    }
  }

  const float* bp = bperm + layer * G4;
#pragma unroll
  for (int fj = 0; fj < 4; ++fj) {
    int col = bx * 128 + (w & 1) * 64 + fj * 16 + (lane & 15);
    float bv = bp[col];
#pragma unroll
    for (int fi = 0; fi < 4; ++fi) {
      int mg = by * 128 + (w >> 1) * 64 + fi * 16 + (lane >> 4) * 4;
#pragma unroll
      for (int r = 0; r < 4; ++r)
        gx[(size_t)(mg + r) * G4 + col] = acc[fi][fj][r] + bv;
    }
  }
}

// ---------------- persistent recurrent chunk v3 ----------------
// 128 WGs x 256 thr (grid <= #CUs => all co-resident). WG (bg,cg):
// bg = wg>>5 -> batches [bg*16, +16); cg = wg&31 -> interleaved cols
// [cg*128, +128) = units [cg*32, +32) x 4 gates. Wave wv: K-range
// [wv*256, +256), all 128 cols, W held in 256 VGPRs (loaded once).
// Per step: poll flags (LLC, relaxed, monotonic) -> load h frags (LLC)
// -> 64 MFMA -> LDS partial-K reduce -> fused LSTM elementwise ->
// coalesced LLC h store -> vmcnt(0)+barrier -> flag store.
__global__ __launch_bounds__(256, 1) void k_steps64(unsigned short* __restrict__ hbf,
                                                    const unsigned short* __restrict__ wbf,
                                                    const float* __restrict__ gx,
                                                    float* __restrict__ cst,
                                                    float* __restrict__ dout,
                                                    unsigned short* __restrict__ xnext,
                                                    unsigned* __restrict__ flags,
                                                    int layer, int t0) {
  __shared__ __align__(16) float gl[4][128][20];      // [wave][col][batch(16)+pad]
  __shared__ unsigned short hstage[16][34];
  __shared__ float fstage[16][33];
  const int tid = threadIdx.x;
  const int lane = tid & 63;
  const int wv = tid >> 6;
  const int wg = blockIdx.x;
  const int bg = wg >> 5, cg = wg & 31;
  const int b0 = bg * 16;
  const int n0 = cg * 128;
  const int u0 = cg * 32;
  const int k0 = wv * 256;
  const unsigned lgen = (unsigned)(layer * TT);

  // ---- W preload: 8 n-tiles x 8 k-slices, 256 VGPRs ----
  bf16x8 wreg[8][8];
  {
    const unsigned short* wbase = wbf + (size_t)layer * G4 * D2;
#pragma unroll
    for (int nt = 0; nt < 8; ++nt) {
      int n = n0 + nt * 16 + (lane & 15);
      const unsigned short* wr = wbase + (size_t)((n & 3) * HH + (n >> 2)) * D2
                                 + HH + k0 + (lane >> 4) * 8;
#pragma unroll
      for (int ks = 0; ks < 8; ++ks)
        wreg[nt][ks] = *(const bf16x8*)(wr + ks * 32);
    }
  }

  // ---- c-state in registers for the whole chunk ----
  const int eb = tid & 15;         // elementwise batch (local)
  const int eua = tid >> 4;        // elementwise unit a (0..15); unit b = +16
  float c_a = cst[(size_t)(b0 + eb) * HH + u0 + eua];
  float c_b = cst[(size_t)(b0 + eb) * HH + u0 + eua + 16];

  for (int tt = 0; tt < TC; ++tt) {
    const int t = t0 + tt;

    // gx prefetch (independent of h) - overlaps poll latency
    const float4 gxa = *(const float4*)(gx + ((size_t)(tt * BB + b0 + eb)) * G4 + (u0 + eua) * 4);
    const float4 gxb = *(const float4*)(gx + ((size_t)(tt * BB + b0 + eb)) * G4 + (u0 + eua + 16) * 4);

    if (tt > 0) {
      if (wv == 0) {
        const unsigned tprev = lgen + (unsigned)t;  // value after step t-1
        const unsigned* f0 = flags + lane;
        const unsigned* f1 = flags + 64 + lane;
        while (1) {
          unsigned a = ld_flag(f0);
          unsigned b = ld_flag(f1);
          if (__all((int)(a >= tprev && b >= tprev))) break;
          __builtin_amdgcn_s_sleep(2);
        }
      }
    }
    __syncthreads();

    // ---- A fragments from LLC ----
    const unsigned short* hsrc = hbf + (size_t)(t & 1) * (BB * HH)
                                 + (size_t)(b0 + (lane & 15)) * HH + k0 + (lane >> 4) * 8;
    bf16x8 areg[8];
#pragma unroll
    for (int ks = 0; ks < 8; ++ks) areg[ks] = ld_h16(hsrc + ks * 32);
    asm volatile("s_waitcnt vmcnt(0)" ::: "memory");
    __builtin_amdgcn_sched_barrier(0);

    // ---- 64 MFMA: 8 col-tiles x 8 k-slices ----
    f32x4 acc[8] = {};
#pragma unroll
    for (int ks = 0; ks < 8; ++ks)
#pragma unroll
      for (int nt = 0; nt < 8; ++nt)
        acc[nt] = __builtin_amdgcn_mfma_f32_16x16x32_bf16(areg[ks], wreg[nt][ks], acc[nt], 0, 0, 0);

    // ---- partial-K write: [col][batch] col-major, b128 ----
    {
      float* gw = &gl[wv][0][0];
#pragma unroll
      for (int nt = 0; nt < 8; ++nt) {
        int col = nt * 16 + (lane & 15);
        *(f32x4*)&gw[col * 20 + (lane >> 4) * 4] = acc[nt];
      }
    }
    __syncthreads();

    // ---- reduce 4 partials ----
#pragma unroll
    for (int rep = 0; rep < 2; ++rep) {
      int idx = rep * 256 + tid;           // 0..511
      int col = idx >> 2, b4 = (idx & 3) * 4;
      f32x4 s = *(const f32x4*)&gl[0][col][b4];
      s += *(const f32x4*)&gl[1][col][b4];
      s += *(const f32x4*)&gl[2][col][b4];
      s += *(const f32x4*)&gl[3][col][b4];
      *(f32x4*)&gl[0][col][b4] = s;
    }
    __syncthreads();

    // ---- fused LSTM elementwise (2 units per thread) ----
    {
      const float* g0 = &gl[0][0][0];
      // unit a
      {
        int ul = eua;
        float fg = g0[(ul * 4 + 0) * 20 + eb] + gxa.x;
        float ig = g0[(ul * 4 + 1) * 20 + eb] + gxa.y;
        float gg = g0[(ul * 4 + 2) * 20 + eb] + gxa.z;
        float og = g0[(ul * 4 + 3) * 20 + eb] + gxa.w;
        float cn = sigm(fg) * c_a + sigm(ig) * tanhfast(gg);
        float hn = sigm(og) * tanhfast(cn);
        c_a = cn;
        hstage[eb][ul] = f2bf(hn);
        if (layer == 1) fstage[eb][ul] = hn;
        else if (t == TT - 1) dout[((size_t)(b0 + eb) * TT + t) * HH + u0 + ul] = hn;
      }
      // unit b
      {
        int ul = eua + 16;
        float fg = g0[(ul * 4 + 0) * 20 + eb] + gxb.x;
        float ig = g0[(ul * 4 + 1) * 20 + eb] + gxb.y;
        float gg = g0[(ul * 4 + 2) * 20 + eb] + gxb.z;
        float og = g0[(ul * 4 + 3) * 20 + eb] + gxb.w;
        float cn = sigm(fg) * c_b + sigm(ig) * tanhfast(gg);
        float hn = sigm(og) * tanhfast(cn);
        c_b = cn;
        hstage[eb][ul] = f2bf(hn);
        if (layer == 1) fstage[eb][ul] = hn;
        else if (t == TT - 1) dout[((size_t)(b0 + eb) * TT + t) * HH + u0 + ul] = hn;
      }
    }
    __syncthreads();

    // ---- coalesced h store (LLC) + xnext/dout ----
    {
      int b = tid >> 4, pr = tid & 15;
      unsigned v2 = *(const unsigned*)&hstage[b][pr * 2];
      unsigned short* hdst = hbf + (size_t)((t + 1) & 1) * (BB * HH)
                             + (size_t)(b0 + b) * HH + u0 + pr * 2;
      st_h32(hdst, v2);
      if (layer == 0)
        *(unsigned*)(xnext + ((size_t)(b0 + b) * TT + t) * HH + u0 + pr * 2) = v2;
    }
    if (layer == 1) {
#pragma unroll
      for (int rep = 0; rep < 2; ++rep) {
        int item = rep * 256 + tid;
        int b = item >> 5, ul = item & 31;
        dout[((size_t)(b0 + b) * TT + t) * HH + u0 + ul] = fstage[b][ul];
      }
    }

    asm volatile("s_waitcnt vmcnt(0)" ::: "memory");
    __syncthreads();
    if (tid == 0) st_flag(flags + wg, lgen + (unsigned)t + 1u);
  }

  // ---- write back c-state ----
  cst[(size_t)(b0 + eb) * HH + u0 + eua] = c_a;
  cst[(size_t)(b0 + eb) * HH + u0 + eua + 16] = c_b;
}

// h_n[l] = out[:, T-1, :], c_n[l] = c_state
__global__ void k_finals(const float* __restrict__ cst, float* __restrict__ dout, int layer) {
  int i = blockIdx.x * blockDim.x + threadIdx.x;
  if (i < BB * HH) {
    int b = i >> 10, u = i & 1023;
    dout[(size_t)BB * TT * HH + (size_t)layer * BB * HH + i] =
        dout[((size_t)b * TT + (TT - 1)) * HH + u];
    dout[(size_t)BB * TT * HH + (size_t)NL * BB * HH + (size_t)layer * BB * HH + i] = cst[i];
  }
}

extern "C" void kernel_launch(void* const* d_in, const int* in_sizes, int n_in,
                              void* d_out, int out_size, void* d_ws, size_t ws_size,
                              hipStream_t stream) {
  const float* x = (const float*)d_in[0];
  const float* W = (const float*)d_in[1];
  const float* bias = (const float*)d_in[2];
  const float* h0 = (const float*)d_in[3];
  const float* c0 = (const float*)d_in[4];
  float* out = (float*)d_out;

  char* ws = (char*)d_ws;
  unsigned short* wbf = (unsigned short*)(ws + 0);            // 33,554,432 B
  unsigned short* xbf = (unsigned short*)(ws + 33554432);     // 67,108,864 B
  float* gx = (float*)(ws + 100663296);                       // 67,108,864 B
  unsigned short* hbf = (unsigned short*)(ws + 167772160);    // 262,144 B
  float* cst = (float*)(ws + 168034304);                      // 262,144 B
  float* bperm = (float*)(ws + 168296448);                    // 32,768 B
  unsigned* flags = (unsigned*)(ws + 168329216);              // 512 B (128 uints)

  k_zero<<<1, 128, 0, stream>>>(flags, 128);
  k_cvt<<<2048, 256, 0, stream>>>(W, wbf, NL * G4 * D2 / 4);
  k_cvt<<<2048, 256, 0, stream>>>(x, xbf, BB * TT * HH / 4);
  k_biasperm<<<(NL * G4 + 255) / 256, 256, 0, stream>>>(bias, bperm);

  for (int l = 0; l < NL; ++l) {
    k_init<<<BB * HH / 256, 256, 0, stream>>>(h0, c0, hbf, cst, l);
    for (int c = 0; c < NCHUNK; ++c) {
      k_xgemm<<<dim3(32, 32), 256, 0, stream>>>(xbf, wbf, bperm, gx, l, c * TC);
      k_steps64<<<128, 256, 0, stream>>>(hbf, wbf, gx, cst, out,
                                         (l == 0) ? xbf : (unsigned short*)nullptr,
                                         flags, l, c * TC);
    }
    k_finals<<<256, 256, 0, stream>>>(cst, out, l);
  }
}